// Round 2
// baseline (274.764 us; speedup 1.0000x reference)
//
#include <hip/hip_runtime.h>
#include <hip/hip_bf16.h>

// Problem constants (fixed by setup_inputs):
//   B=32, T=1024, N=1024, R=8, C=32, NPR=128, RKEEP=6, HID=1024, NLAT=160
// out[b,t,l] = sum_{r in ids_shuffle[b,0:6]} sum_n spikes[b,t,r*128+n]*F[l,r*128+n]
//              + bias0[l] + sum_{r active} bias_area[l,r]
// F = (V_W@U_W) folded with W_area; computed on device each launch (no state).

typedef float f32x4 __attribute__((ext_vector_type(4)));
typedef __bf16 bf16x8 __attribute__((ext_vector_type(8)));

#define KSPLIT 16

// ---------------- P_A: M partials = V_W (160x1024) @ U_W (1024x256), K-split 16
// grid 640 = 40 l-quads x 16 k-chunks; M_part[ck][l][rc] fp32
__global__ __launch_bounds__(256) void pa_kernel(const float* __restrict__ V_W,
                                                 const float* __restrict__ U_W,
                                                 float* __restrict__ M_part) {
    const int rc = threadIdx.x;
    const int lq = blockIdx.x >> 4;   // 0..39
    const int ck = blockIdx.x & 15;   // 0..15
    const int l0 = lq * 4;
    const int h0 = ck * 64;
    float a0 = 0.f, a1 = 0.f, a2 = 0.f, a3 = 0.f;
#pragma unroll 8
    for (int hh = 0; hh < 64; ++hh) {
        const int h = h0 + hh;
        const float u = U_W[h * 256 + rc];          // coalesced, L2-hot
        a0 += V_W[(l0 + 0) * 1024 + h] * u;         // uniform -> s_loads
        a1 += V_W[(l0 + 1) * 1024 + h] * u;
        a2 += V_W[(l0 + 2) * 1024 + h] * u;
        a3 += V_W[(l0 + 3) * 1024 + h] * u;
    }
    float* dst = M_part + (size_t)ck * 160 * 256;
    dst[(l0 + 0) * 256 + rc] = a0;
    dst[(l0 + 1) * 256 + rc] = a1;
    dst[(l0 + 2) * 256 + rc] = a2;
    dst[(l0 + 3) * 256 + rc] = a3;
}

// ---------------- P_B: per (l, rn-quarter): reduce M partials, fold with W_area
// -> F(bf16). grid 640 = 160 l x 4 rn-quarters, 256 threads (1 rn each).
// p4==0 blocks also emit bias_area[l][r] and bias0[l].
__global__ __launch_bounds__(256) void pb_kernel(const float* __restrict__ M_part,
                                                 const float* __restrict__ W_area,
                                                 const float* __restrict__ b_area,
                                                 const float* __restrict__ V_W,
                                                 const float* __restrict__ U_b,
                                                 const float* __restrict__ V_b,
                                                 __bf16* __restrict__ F,
                                                 float* __restrict__ bias_area,
                                                 float* __restrict__ bias0) {
    const int l = blockIdx.x >> 2;
    const int p4 = blockIdx.x & 3;
    const int tid = threadIdx.x;
    __shared__ float Mrow[256];
    __shared__ float red[256];

    // phase 0: sum the K-split partials -> final M row (256 floats)
    float m = 0.f;
#pragma unroll
    for (int p = 0; p < KSPLIT; ++p) m += M_part[(size_t)(p * 160 + l) * 256 + tid];
    Mrow[tid] = m;

    // bias0 partial: V_W[l,:] . U_b (U_b is zeros here; kept for generality)
    float p0 = 0.f;
#pragma unroll
    for (int hh = 0; hh < 4; ++hh) {
        const int h = tid + hh * 256;
        p0 += V_W[(size_t)l * 1024 + h] * U_b[h];
    }
    red[tid] = p0;
    __syncthreads();

    // phase 1: F[l][rn] = sum_c Mrow[r*32+c] * W_area[r,c,n]; one rn per thread
    {
        const int rn = p4 * 256 + tid;
        const int r = rn >> 7, n = rn & 127;
        float acc = 0.f;
#pragma unroll
        for (int c = 0; c < 32; ++c)
            acc += Mrow[r * 32 + c] * W_area[((r * 32 + c) << 7) + n];
        F[(size_t)l * 1024 + rn] = (__bf16)acc;
    }

    if (p4 == 0) {
        // phase 2: bias_area[l][r] = sum_c Mrow[r*32+c] * b_area[r,c]
        if (tid < 8) {
            const int r = tid;
            float acc = 0.f;
            for (int c = 0; c < 32; ++c) acc += Mrow[r * 32 + c] * b_area[r * 32 + c];
            bias_area[l * 8 + r] = acc;
        }
        // phase 3: reduce bias0 partials
        for (int off = 128; off > 0; off >>= 1) {
            __syncthreads();
            if (tid < off) red[tid] += red[tid + off];
        }
        if (tid == 0) bias0[l] = V_b[l] + red[0];
    }
}

// ---------------- MAIN: fused masked GEMM.
// grid 1024 blocks x 256 threads (4 waves). Block = 2 token-tiles (16 tokens)
// x 2 nt-halves; wave = 16 tokens x 80 outputs. VGPR target <=128 ->
// 4 waves/SIMD -> 16 waves/CU, all 1024 blocks resident (4 blocks/CU).
// K-loop: 6 active regions x 4 K-steps of 32 (skips masked regions entirely).
__global__ __launch_bounds__(256, 4) void main_kernel(const float* __restrict__ spikes,
                                                      const int* __restrict__ ids,
                                                      const __bf16* __restrict__ F,
                                                      const float* __restrict__ bias_area,
                                                      const float* __restrict__ bias0,
                                                      float* __restrict__ out) {
    const int tid = threadIdx.x;
    const int lane = tid & 63;
    const int wave = tid >> 6;
    const int s = lane & 15;   // A: m index / B: n index / D: col
    const int q = lane >> 4;   // K quad
    const int half = wave & 1;            // nt-half: outputs [half*80, half*80+80)
    const int tt = blockIdx.x * 2 + (wave >> 1);  // token tile 0..2047
    const int tok0 = tt * 16;
    const int b = tok0 >> 10;             // batch

    int rj[6];
#pragma unroll
    for (int j = 0; j < 6; ++j) rj[j] = ids[b * 8 + j];  // active regions (uniform)

    f32x4 acc[5];
#pragma unroll
    for (int nt = 0; nt < 5; ++nt) acc[nt] = (f32x4){0.f, 0.f, 0.f, 0.f};

    const __bf16* Fh = F + (size_t)(half * 80 + s) * 1024;

#pragma unroll 1
    for (int j = 0; j < 6; ++j) {
        const int colbase = rj[j] * 128;
        // Batch the 8 HBM loads for this region up-front (latency overlap):
        // lane covers A[m=s][k=q*8+i] for kk=0..3
        float4 rawA[4][2];
        {
            const float* rowp = spikes + (size_t)(tok0 + s) * 1024 + colbase + q * 8;
#pragma unroll
            for (int kk = 0; kk < 4; ++kk) {
                rawA[kk][0] = *(const float4*)(rowp + kk * 32);
                rawA[kk][1] = *(const float4*)(rowp + kk * 32 + 4);
            }
        }
#pragma unroll
        for (int kk = 0; kk < 4; ++kk) {
            const int col = colbase + kk * 32 + q * 8;
            // B fragments from L2-hot F: B[n=s][k=q*8+i], 16B contiguous
            bf16x8 bf[5];
#pragma unroll
            for (int nt = 0; nt < 5; ++nt)
                bf[nt] = *(const bf16x8*)(Fh + (size_t)nt * 16 * 1024 + col);
            const float4 lo = rawA[kk][0];
            const float4 hi = rawA[kk][1];
            bf16x8 af;
            af[0] = (__bf16)lo.x; af[1] = (__bf16)lo.y;
            af[2] = (__bf16)lo.z; af[3] = (__bf16)lo.w;
            af[4] = (__bf16)hi.x; af[5] = (__bf16)hi.y;
            af[6] = (__bf16)hi.z; af[7] = (__bf16)hi.w;
#pragma unroll
            for (int nt = 0; nt < 5; ++nt)
                acc[nt] = __builtin_amdgcn_mfma_f32_16x16x32_bf16(
                    af, bf[nt], acc[nt], 0, 0, 0);
        }
    }

    // Epilogue: D[row=q*4+i][col=s]; token = tok0 + q*4 + i, l = half*80 + nt*16 + s
#pragma unroll
    for (int nt = 0; nt < 5; ++nt) {
        const int l = half * 80 + nt * 16 + s;
        float bias = bias0[l];
#pragma unroll
        for (int j = 0; j < 6; ++j) bias += bias_area[l * 8 + rj[j]];
        const int tk = tok0 + q * 4;
#pragma unroll
        for (int i = 0; i < 4; ++i)
            out[(size_t)(tk + i) * 160 + l] = acc[nt][i] + bias;
    }
}

extern "C" void kernel_launch(void* const* d_in, const int* in_sizes, int n_in,
                              void* d_out, int out_size, void* d_ws, size_t ws_size,
                              hipStream_t stream) {
    (void)in_sizes; (void)n_in; (void)out_size; (void)ws_size;
    const float* spikes = (const float*)d_in[0];  // (32,1024,1024)
    const float* W_area = (const float*)d_in[1];  // (8,32,128)
    const float* b_area = (const float*)d_in[2];  // (8,32)
    const float* U_W    = (const float*)d_in[3];  // (1024,256)
    const float* U_b    = (const float*)d_in[4];  // (1024,)
    const float* V_W    = (const float*)d_in[5];  // (160,1024)
    const float* V_b    = (const float*)d_in[6];  // (160,)
    const int*   ids    = (const int*)d_in[7];    // (32,8) int32
    float* out = (float*)d_out;                   // (32,1024,160) fp32

    char* ws = (char*)d_ws;
    // M_part: [16][160][256] fp32 = 2,621,440 B
    float*  M_part    = (float*)ws;
    __bf16* F         = (__bf16*)(ws + 2621440);  // [160][1024] bf16 = 327,680 B
    float*  bias_area = (float*)(ws + 2949120);   // [160][8] fp32    = 5,120 B
    float*  bias0     = (float*)(ws + 2954240);   // [160] fp32       = 640 B

    pa_kernel<<<640, 256, 0, stream>>>(V_W, U_W, M_part);
    pb_kernel<<<640, 256, 0, stream>>>(M_part, W_area, b_area, V_W, U_b, V_b,
                                       F, bias_area, bias0);
    main_kernel<<<1024, 256, 0, stream>>>(spikes, ids, F, bias_area, bias0, out);
}

// Round 4
// 236.351 us; speedup vs baseline: 1.1625x; 1.1625x over previous
//
#include <hip/hip_runtime.h>
#include <hip/hip_bf16.h>

// Problem constants (fixed by setup_inputs):
//   B=32, T=1024, N=1024, R=8, C=32, NPR=128, RKEEP=6, HID=1024, NLAT=160
// out[b,t,l] = sum_{r in ids_shuffle[b,0:6]} sum_n spikes[b,t,r*128+n]*F[l,r*128+n]
//              + bias0[l] + sum_{r active} bias_area[l,r]
// F = (V_W@U_W) folded with W_area, stored PACKED in MFMA B-fragment order:
//   F_packed[((r*4+kk)*10+nt)*512 + (q*16+s)*8 + i] = F[nt*16+s][r*128+kk*32+q*8+i]
//   -> every B-fragment load is one contiguous 1KB wave read.

typedef float f32x4 __attribute__((ext_vector_type(4)));
typedef __bf16 bf16x8 __attribute__((ext_vector_type(8)));

#define KSPLIT 16

// ---------------- P_A: M partials = V_W (160x1024) @ U_W (1024x256), K-split 16
__global__ __launch_bounds__(256) void pa_kernel(const float* __restrict__ V_W,
                                                 const float* __restrict__ U_W,
                                                 float* __restrict__ M_part) {
    const int rc = threadIdx.x;
    const int lq = blockIdx.x >> 4;   // 0..39
    const int ck = blockIdx.x & 15;   // 0..15
    const int l0 = lq * 4;
    const int h0 = ck * 64;
    float a0 = 0.f, a1 = 0.f, a2 = 0.f, a3 = 0.f;
#pragma unroll 8
    for (int hh = 0; hh < 64; ++hh) {
        const int h = h0 + hh;
        const float u = U_W[h * 256 + rc];          // coalesced, L2-hot
        a0 += V_W[(l0 + 0) * 1024 + h] * u;         // uniform -> s_loads
        a1 += V_W[(l0 + 1) * 1024 + h] * u;
        a2 += V_W[(l0 + 2) * 1024 + h] * u;
        a3 += V_W[(l0 + 3) * 1024 + h] * u;
    }
    float* dst = M_part + (size_t)ck * 160 * 256;
    dst[(l0 + 0) * 256 + rc] = a0;
    dst[(l0 + 1) * 256 + rc] = a1;
    dst[(l0 + 2) * 256 + rc] = a2;
    dst[(l0 + 3) * 256 + rc] = a3;
}

// ---------------- P_B: reduce M partials, fold with W_area -> F_packed(bf16).
// grid 640 = 160 l x 4 rn-quarters, 256 threads (1 rn each).
__global__ __launch_bounds__(256) void pb_kernel(const float* __restrict__ M_part,
                                                 const float* __restrict__ W_area,
                                                 const float* __restrict__ b_area,
                                                 const float* __restrict__ V_W,
                                                 const float* __restrict__ U_b,
                                                 const float* __restrict__ V_b,
                                                 __bf16* __restrict__ F_packed,
                                                 float* __restrict__ bias_area,
                                                 float* __restrict__ bias0) {
    const int l = blockIdx.x >> 2;
    const int p4 = blockIdx.x & 3;
    const int tid = threadIdx.x;
    __shared__ float Mrow[256];
    __shared__ float red[256];

    float m = 0.f;
#pragma unroll
    for (int p = 0; p < KSPLIT; ++p) m += M_part[(size_t)(p * 160 + l) * 256 + tid];
    Mrow[tid] = m;

    float p0 = 0.f;
#pragma unroll
    for (int hh = 0; hh < 4; ++hh) {
        const int h = tid + hh * 256;
        p0 += V_W[(size_t)l * 1024 + h] * U_b[h];
    }
    red[tid] = p0;
    __syncthreads();

    // F_packed[((r*4+kk)*10+nt)*512 + (q*16+s)*8 + i], n = kk*32+q*8+i, l = nt*16+s
    {
        const int rn = p4 * 256 + tid;
        const int r = rn >> 7, n = rn & 127;
        float acc = 0.f;
#pragma unroll
        for (int c = 0; c < 32; ++c)
            acc += Mrow[r * 32 + c] * W_area[((r * 32 + c) << 7) + n];
        const int kk = n >> 5, q = (n >> 3) & 3, i = n & 7;
        const int nt = l >> 4, s = l & 15;
        const size_t idx = ((size_t)(r * 4 + kk) * 10 + nt) * 512 + (q * 16 + s) * 8 + i;
        F_packed[idx] = (__bf16)acc;
    }

    if (p4 == 0) {
        if (tid < 8) {
            const int r = tid;
            float acc = 0.f;
            for (int c = 0; c < 32; ++c) acc += Mrow[r * 32 + c] * b_area[r * 32 + c];
            bias_area[l * 8 + r] = acc;
        }
        for (int off = 128; off > 0; off >>= 1) {
            __syncthreads();
            if (tid < off) red[tid] += red[tid + off];
        }
        if (tid == 0) bias0[l] = V_b[l] + red[0];
    }
}

// ---------------- MAIN: fused masked GEMM, software-pipelined.
// grid 1024 blocks x 128 threads (2 waves). Wave = 16 tokens x 160 latents.
// A staged wave-private via global_load_lds into DOUBLE-BUFFERED LDS: iteration
// j prefetches region j+1 into buf (j+1)&1, then `s_waitcnt vmcnt(8)` drains
// everything older than the 8 just-issued DMAs (FIFO retirement) -> region j's
// tile is landed, region j+1 stays in flight behind compute. The "memory"
// clobber pins ds_read ordering (R3's bug: no wait, reads hoisted over the DMA).
// No __syncthreads anywhere. WAR safe: buf reused 2 iterations later, reads
// retired via lgkmcnt before the next DMA issue.
__global__ __launch_bounds__(128, 2) void main_kernel(const float* __restrict__ spikes,
                                                      const int* __restrict__ ids,
                                                      const __bf16* __restrict__ Fp,
                                                      const float* __restrict__ bias_area,
                                                      const float* __restrict__ bias0,
                                                      float* __restrict__ out) {
    const int tid = threadIdx.x;
    const int lane = tid & 63;
    const int wave = tid >> 6;            // 0..1
    const int s = lane & 15;              // A: m / B: n / D: col
    const int q = lane >> 4;              // K quad
    const int tokw = blockIdx.x * 32 + wave * 16;  // wave's first token
    const int b = blockIdx.x >> 5;        // batch (32 blocks per batch)

    // [wave][buf][16 rows x 128 floats]: instr i writes rows {2i,2i+1};
    // row s float f at (s>>1)*256 + (s&1)*128 + f
    __shared__ float tile[2][2][2048];

    int rj[6];
#pragma unroll
    for (int j = 0; j < 6; ++j) rj[j] = ids[b * 8 + j];

    f32x4 acc[10];
#pragma unroll
    for (int nt = 0; nt < 10; ++nt) acc[nt] = (f32x4){0.f, 0.f, 0.f, 0.f};

    const int r2 = lane >> 5;    // row within pair
    const int c32 = lane & 31;   // 16B chunk within row

    // stage region reg's 16x128 A-tile into tile[wave][buf]: 8 async 1KB DMAs,
    // each = two contiguous 512B row segments, zero VGPR destinations.
    auto stage = [&](int buf, int reg) {
        const float* src = spikes + (size_t)(tokw + r2) * 1024 + reg * 128 + c32 * 4;
        float* ldsw = &tile[wave][buf][0];
#pragma unroll
        for (int i = 0; i < 8; ++i)
            __builtin_amdgcn_global_load_lds(
                (const __attribute__((address_space(1))) float*)(src + i * 2048),
                (__attribute__((address_space(3))) float*)(ldsw + i * 256),
                16, 0, 0);
    };

    stage(0, rj[0]);  // prologue

#pragma unroll 1
    for (int j = 0; j < 6; ++j) {
        if (j < 5) stage((j + 1) & 1, rj[j + 1]);   // prefetch next region
        // Drain all but the 8 newest VMEM ops: current tile landed, prefetch
        // stays outstanding. (j==5: older ops already drained by j==4's B-load
        // waits, FIFO retirement -> no-op.)
        asm volatile("s_waitcnt vmcnt(8)" ::: "memory");

        const float* arow = &tile[wave][j & 1][(s >> 1) * 256 + (s & 1) * 128];
#pragma unroll
        for (int kk = 0; kk < 4; ++kk) {
            // B fragments: one contiguous 1KB wave read each (L2/L1-hot)
            bf16x8 bfr[10];
            const __bf16* fb = Fp + ((size_t)(rj[j] * 4 + kk) * 10) * 512 + lane * 8;
#pragma unroll
            for (int nt = 0; nt < 10; ++nt)
                bfr[nt] = *(const bf16x8*)(fb + nt * 512);
            // A fragment from landed LDS tile
            const f32x4 a0 = *(const f32x4*)(arow + kk * 32 + q * 8);
            const f32x4 a1 = *(const f32x4*)(arow + kk * 32 + q * 8 + 4);
            bf16x8 af;
            af[0] = (__bf16)a0.x; af[1] = (__bf16)a0.y;
            af[2] = (__bf16)a0.z; af[3] = (__bf16)a0.w;
            af[4] = (__bf16)a1.x; af[5] = (__bf16)a1.y;
            af[6] = (__bf16)a1.z; af[7] = (__bf16)a1.w;
#pragma unroll
            for (int nt = 0; nt < 10; ++nt)
                acc[nt] = __builtin_amdgcn_mfma_f32_16x16x32_bf16(
                    af, bfr[nt], acc[nt], 0, 0, 0);
        }
    }

    // Epilogue: D[row=q*4+i][col=s]; token = tokw + q*4 + i, l = nt*16 + s
#pragma unroll
    for (int nt = 0; nt < 10; ++nt) {
        const int l = nt * 16 + s;
        float bias = bias0[l];
#pragma unroll
        for (int j = 0; j < 6; ++j) bias += bias_area[l * 8 + rj[j]];
        const int tk = tokw + q * 4;
#pragma unroll
        for (int i = 0; i < 4; ++i)
            out[(size_t)(tk + i) * 160 + l] = acc[nt][i] + bias;
    }
}

extern "C" void kernel_launch(void* const* d_in, const int* in_sizes, int n_in,
                              void* d_out, int out_size, void* d_ws, size_t ws_size,
                              hipStream_t stream) {
    (void)in_sizes; (void)n_in; (void)out_size; (void)ws_size;
    const float* spikes = (const float*)d_in[0];  // (32,1024,1024)
    const float* W_area = (const float*)d_in[1];  // (8,32,128)
    const float* b_area = (const float*)d_in[2];  // (8,32)
    const float* U_W    = (const float*)d_in[3];  // (1024,256)
    const float* U_b    = (const float*)d_in[4];  // (1024,)
    const float* V_W    = (const float*)d_in[5];  // (160,1024)
    const float* V_b    = (const float*)d_in[6];  // (160,)
    const int*   ids    = (const int*)d_in[7];    // (32,8) int32
    float* out = (float*)d_out;                   // (32,1024,160) fp32

    char* ws = (char*)d_ws;
    float*  M_part    = (float*)ws;               // [16][160][256] fp32 = 2,621,440 B
    __bf16* F_packed  = (__bf16*)(ws + 2621440);  // 163,840 bf16 = 327,680 B
    float*  bias_area = (float*)(ws + 2949120);   // [160][8] fp32 = 5,120 B
    float*  bias0     = (float*)(ws + 2954240);   // [160] fp32 = 640 B

    pa_kernel<<<640, 256, 0, stream>>>(V_W, U_W, M_part);
    pb_kernel<<<640, 256, 0, stream>>>(M_part, W_area, b_area, V_W, U_b, V_b,
                                       F_packed, bias_area, bias0);
    main_kernel<<<1024, 128, 0, stream>>>(spikes, ids, F_packed, bias_area, bias0, out);
}